// Round 9
// baseline (147.195 us; speedup 1.0000x reference)
//
#include <hip/hip_runtime.h>

// SQDDPG mixer, MI355X. Round 9: M=128 single sweep with 8-wave (512-thr)
// blocks — R6's traffic savings at R5's 16 waves/CU occupancy. Single-i
// column loop keeps regs <=128 at __launch_bounds__(512,4) (R4 lesson).
//
// Frozen validated facts (R2..R8 passes): threefry partitionable,
// bits=o0^o1, counter (0, b*128+n); stable ranks; coalition slot j <-
// qs[inv_l[j]]; output agent n reads prefix-row pos_l[n]; A-frag
// A[m=l15][k=t*32+q*8+j]; C-frag row=q*4+r col=l15; B-frag pack: slot
// (t,u,L) elem j -> B[k=t*32+(L>>4)*8+j][n=u*16+(L&15)]; mt-width-8
// h1 scatter/read (R6); adv row = s*8+prefix (R6).

#define A_N   8
#define NA_N  16
#define S_N   16
#define SD    256
#define EMB   256
#define B_TOT 1024

typedef __bf16 bf16x8 __attribute__((ext_vector_type(8)));
typedef float  f32x4  __attribute__((ext_vector_type(4)));

__device__ __forceinline__ f32x4 splat4(float v) {
  f32x4 x; x[0] = v; x[1] = v; x[2] = v; x[3] = v; return x;
}
__device__ __forceinline__ bf16x8 zero8() {
  bf16x8 z;
#pragma unroll
  for (int j = 0; j < 8; ++j) z[j] = (__bf16)0.0f;
  return z;
}

// ---------------------------------------------------------------------------
// JAX threefry2x32, key = (0, 42); partitionable draw: bits = o0 ^ o1.
// ---------------------------------------------------------------------------
__device__ __forceinline__ float jax_uniform(unsigned idx) {
  const unsigned ks0 = 0u, ks1 = 42u, ks2 = 0x1BD11BDAu ^ 42u;
  unsigned x0 = 0u + ks0;
  unsigned x1 = idx + ks1;
#define TF_RND(r) { x0 += x1; x1 = (x1 << (r)) | (x1 >> (32 - (r))); x1 ^= x0; }
  TF_RND(13) TF_RND(15) TF_RND(26) TF_RND(6)  x0 += ks1; x1 += ks2 + 1u;
  TF_RND(17) TF_RND(29) TF_RND(16) TF_RND(24) x0 += ks2; x1 += ks0 + 2u;
  TF_RND(13) TF_RND(15) TF_RND(26) TF_RND(6)  x0 += ks0; x1 += ks1 + 3u;
  TF_RND(17) TF_RND(29) TF_RND(16) TF_RND(24) x0 += ks1; x1 += ks2 + 4u;
  TF_RND(13) TF_RND(15) TF_RND(26) TF_RND(6)  x0 += ks2; x1 += ks0 + 5u;
#undef TF_RND
  const unsigned bits = x0 ^ x1;
  return __uint_as_float((bits >> 9) | 0x3F800000u) - 1.0f;
}

// ---------------------------------------------------------------------------
// One launch: blocks 0..47 pack W1b_bf + W2_bf; blocks 48..111 = MFMA prep
// (16 M-tiles x 4 N-strips of [W1top|Vw1], B-frags built on the fly).
// Strips 0,1 -> sW; strips 2,3 -> relu()*Vw2 reduced -> vpart[ni-2][row].
// (Unchanged from R8 — proven.)
// ---------------------------------------------------------------------------
__global__ __launch_bounds__(256) void prep_pack_kernel(
    const float* __restrict__ states, const float* __restrict__ W1,
    const float* __restrict__ b1, const float* __restrict__ W2,
    const float* __restrict__ Vw1, const float* __restrict__ Vb1,
    const float* __restrict__ Vw2, float* __restrict__ sW,
    float* __restrict__ vpart, __bf16* __restrict__ W1b_bf,
    __bf16* __restrict__ W2_bf) {
  const int n = threadIdx.x;

  if (blockIdx.x < 48) {
    const int ts = blockIdx.x * 256 + n;            // 0..12287
    if (ts < 4096) {                                // W1 bottom: t=0..3
      const int t = ts >> 10, rem = ts & 1023, u = rem >> 6, L = rem & 63;
      const int q = L >> 4, l15 = L & 15;
#pragma unroll
      for (int j = 0; j < 8; ++j) {
        const int k = t * 32 + q * 8 + j, nn = u * 16 + l15;
        W1b_bf[ts * 8 + j] = (__bf16)W1[(SD + k) * EMB + nn];
      }
    } else {                                        // W2: t=0..7
      const int ts2 = ts - 4096;
      const int t = ts2 >> 10, rem = ts2 & 1023, u = rem >> 6, L = rem & 63;
      const int q = L >> 4, l15 = L & 15;
#pragma unroll
      for (int j = 0; j < 8; ++j) {
        const int k = t * 32 + q * 8 + j, nn = u * 16 + l15;
        W2_bf[ts2 * 8 + j] = (__bf16)W2[k * EMB + nn];
      }
    }
    return;
  }

  __shared__ float vred[4][64];
  const int blk = blockIdx.x - 48;  // 0..63
  const int mi = blk >> 2;          // 0..15
  const int ni = blk & 3;           // 0..3
  const int w = n >> 6, L = n & 63, q = L >> 4, l15 = L & 15;

  f32x4 acc[4][2];
#pragma unroll
  for (int ui = 0; ui < 2; ++ui) {
    const int col = (ni * 8 + w * 2 + ui) * 16 + l15;  // 0..511
    const float bias = (col < EMB) ? b1[col] : Vb1[col - EMB];
#pragma unroll
    for (int mt = 0; mt < 4; ++mt) acc[mt][ui] = splat4(bias);
  }

#pragma unroll 2
  for (int t = 0; t < 8; ++t) {
    bf16x8 bfr[2];
#pragma unroll
    for (int ui = 0; ui < 2; ++ui) {
      const int nn = (ni * 8 + w * 2 + ui) * 16 + l15;  // 0..511
#pragma unroll
      for (int j = 0; j < 8; ++j) {
        const int k = t * 32 + q * 8 + j;
        const float v = (nn < EMB) ? W1[k * EMB + nn]
                                   : Vw1[k * EMB + (nn - EMB)];
        bfr[ui][j] = (__bf16)v;
      }
    }
#pragma unroll
    for (int mt = 0; mt < 4; ++mt) {
      const float* srow =
          &states[(mi * 64 + mt * 16 + l15) * SD + t * 32 + q * 8];
      bf16x8 af;
#pragma unroll
      for (int j = 0; j < 8; ++j) af[j] = (__bf16)srow[j];
#pragma unroll
      for (int ui = 0; ui < 2; ++ui)
        acc[mt][ui] = __builtin_amdgcn_mfma_f32_16x16x32_bf16(
            af, bfr[ui], acc[mt][ui], 0, 0, 0);
    }
  }

  if (ni < 2) {
#pragma unroll
    for (int ui = 0; ui < 2; ++ui) {
      const int col = (ni * 8 + w * 2 + ui) * 16 + l15;
#pragma unroll
      for (int mt = 0; mt < 4; ++mt)
#pragma unroll
        for (int r = 0; r < 4; ++r)
          sW[(mi * 64 + mt * 16 + q * 4 + r) * EMB + col] = acc[mt][ui][r];
    }
  } else {
#pragma unroll
    for (int mt = 0; mt < 4; ++mt) {
#pragma unroll
      for (int r = 0; r < 4; ++r) {
        float p = 0.f;
#pragma unroll
        for (int ui = 0; ui < 2; ++ui) {
          const int colV = (ni * 8 + w * 2 + ui) * 16 + l15 - EMB;
          p = fmaf(fmaxf(acc[mt][ui][r], 0.f), Vw2[colV], p);
        }
#pragma unroll
        for (int off = 1; off < 16; off <<= 1) p += __shfl_xor(p, off);
        if (l15 == 0) vred[w][mt * 16 + q * 4 + r] = p;
      }
    }
    __syncthreads();
    if (n < 64)
      vpart[(ni - 2) * B_TOT + mi * 64 + n] =
          vred[0][n] + vred[1][n] + vred[2][n] + vred[3][n];
  }
}

// ---------------------------------------------------------------------------
// Main: 1024 blocks (one per b), 512 threads = 8 waves. ONE M=128 sweep:
// wave w owns 32 cols (u = w*2+i, i=0..1 sequential). mt = 0..7 row-tiles.
// ---------------------------------------------------------------------------
__global__ __launch_bounds__(512, 4) void main_kernel(
    const float* __restrict__ agent_qs, const float* __restrict__ b2g,
    const float* __restrict__ W3, const float* __restrict__ b3,
    const float* __restrict__ Vb2, const float* __restrict__ sW,
    const float* __restrict__ vpart, const __bf16* __restrict__ W1b_bf,
    const __bf16* __restrict__ W2_bf, float* __restrict__ out) {
  __shared__ bf16x8 h1_l[64 * 64];      // 64 KB: layer2 A-frags (M=128,K=256)
  __shared__ __attribute__((aligned(16))) __bf16 qs_bf[A_N * NA_N];
  __shared__ float u_l[128];
  __shared__ int   inv_l[128];          // inv_l[s*8+a] = rank of agent a
  __shared__ int   pos_l[128];          // pos_l[s*8+r] = agent with rank r
  __shared__ float adv_part[8][128];    // [wave][row = s*8 + prefix]

  const int b = blockIdx.x;
  const int n = threadIdx.x;
  const int w = n >> 6, L = n & 63, q = L >> 4, l15 = L & 15;

  if (n < 128) {
    qs_bf[n] = (__bf16)agent_qs[b * 128 + n];
    u_l[n] = jax_uniform((unsigned)(b * 128 + n));
  }
  // hoisted per-column constants (cols c = (w*2+i)*16 + l15)
  float sWv[2], b2v[2], w3v[2];
#pragma unroll
  for (int i = 0; i < 2; ++i) {
    const int c = (w * 2 + i) * 16 + l15;
    sWv[i] = sW[b * EMB + c];
    b2v[i] = b2g[c];
    w3v[i] = W3[c];
  }
  __syncthreads();

  if (n < 128) {
    const int s = n >> 3, a = n & 7;
    const float u = u_l[n];
    int r = 0;
#pragma unroll
    for (int a2 = 0; a2 < A_N; ++a2) {
      const float u2 = u_l[s * 8 + a2];
      r += (u2 < u || (u2 == u && a2 < a)) ? 1 : 0;
    }
    inv_l[n] = r;
    pos_l[s * 8 + r] = a;
  }
  __syncthreads();

  const int i_pref  = l15 & 7;     // prefix length of this lane's A-row
  const int sl_half = l15 >> 3;    // which s within the mt pair
  const int jq      = q >> 1;      // jcoal low bit
  const int na0     = (q & 1) * 8; // action sub-block

  // ---- layer 1: (128x128) @ W1b (128x256), C init sW[col]; i sequential --
#pragma unroll 1
  for (int i = 0; i < 2; ++i) {
    const int u = w * 2 + i;
    f32x4 acc[8];
#pragma unroll
    for (int mt = 0; mt < 8; ++mt) acc[mt] = splat4(sWv[i]);
#pragma unroll 2
    for (int t = 0; t < 4; ++t) {
      const int jcoal = t * 2 + jq;
      const bool on = (jcoal <= i_pref);
      const bf16x8 bfr = *(const bf16x8*)&W1b_bf[((t * 16 + u) * 64 + L) * 8];
#pragma unroll
      for (int mt = 0; mt < 8; ++mt) {
        const int ag = inv_l[(mt * 2 + sl_half) * 8 + jcoal];
        const bf16x8 qv = *(const bf16x8*)&qs_bf[ag * NA_N + na0];
        const bf16x8 af = on ? qv : zero8();
        acc[mt] = __builtin_amdgcn_mfma_f32_16x16x32_bf16(af, bfr, acc[mt],
                                                          0, 0, 0);
      }
    }
    // relu -> bf16 scatter into layer2 A-frag layout (mt-width 8, frozen)
    __bf16* h1e = (__bf16*)h1_l;
    const int c = u * 16 + l15;
    const int t2 = c >> 5, q2 = (c >> 3) & 3, j2 = l15 & 7;
#pragma unroll
    for (int mt = 0; mt < 8; ++mt) {
#pragma unroll
      for (int r = 0; r < 4; ++r) {
        const float v = fmaxf(acc[mt][r], 0.f);
        h1e[(((t2 * 8 + mt) * 64) + q2 * 16 + q * 4 + r) * 8 + j2] = (__bf16)v;
      }
    }
  }
  __syncthreads();  // h1 visible to all waves

  // ---- layer 2 + layer 3 partials: i sequential, psum across both ----
  float psum[8][4];
#pragma unroll
  for (int mt = 0; mt < 8; ++mt)
#pragma unroll
    for (int r = 0; r < 4; ++r) psum[mt][r] = 0.f;

#pragma unroll 1
  for (int i = 0; i < 2; ++i) {
    const int u = w * 2 + i;
    f32x4 acc[8];
#pragma unroll
    for (int mt = 0; mt < 8; ++mt) acc[mt] = splat4(b2v[i]);
#pragma unroll 2
    for (int t = 0; t < 8; ++t) {
      const bf16x8 bfr = *(const bf16x8*)&W2_bf[((t * 16 + u) * 64 + L) * 8];
#pragma unroll
      for (int mt = 0; mt < 8; ++mt) {
        const bf16x8 af = h1_l[(t * 8 + mt) * 64 + L];
        acc[mt] = __builtin_amdgcn_mfma_f32_16x16x32_bf16(af, bfr, acc[mt],
                                                          0, 0, 0);
      }
    }
#pragma unroll
    for (int mt = 0; mt < 8; ++mt)
#pragma unroll
      for (int r = 0; r < 4; ++r)
        psum[mt][r] = fmaf(fmaxf(acc[mt][r], 0.f), w3v[i], psum[mt][r]);
  }

  // ---- 16-col shuffle reduce; per-wave partials into adv_part ----
#pragma unroll
  for (int mt = 0; mt < 8; ++mt) {
#pragma unroll
    for (int r = 0; r < 4; ++r) {
      float sum = psum[mt][r];
#pragma unroll
      for (int off = 1; off < 16; off <<= 1) sum += __shfl_xor(sum, off);
      if (l15 == 0) adv_part[w][mt * 16 + q * 4 + r] = sum;
    }
  }
  __syncthreads();

  // ---- gather: agent a reads row s*8 + pos_l[s*8+a], sums 8 waves ----
  if (n < A_N) {
    float sh = 0.f;
#pragma unroll
    for (int s = 0; s < S_N; ++s) {
      const int idx = s * 8 + pos_l[s * 8 + n];
      float v = 0.f;
#pragma unroll
      for (int ww = 0; ww < 8; ++ww) v += adv_part[ww][idx];
      sh += v;
    }
    out[b * A_N + n] = sh * (1.f / 16.f) + b3[0] + Vb2[0] +
                       vpart[b] + vpart[B_TOT + b];
  }
}

// ---------------------------------------------------------------------------
extern "C" void kernel_launch(void* const* d_in, const int* in_sizes, int n_in,
                              void* d_out, int out_size, void* d_ws,
                              size_t ws_size, hipStream_t stream) {
  const float* states   = (const float*)d_in[0];
  const float* agent_qs = (const float*)d_in[1];
  const float* W1       = (const float*)d_in[2];
  const float* b1       = (const float*)d_in[3];
  const float* W2       = (const float*)d_in[4];
  const float* b2       = (const float*)d_in[5];
  const float* W3       = (const float*)d_in[6];
  const float* b3       = (const float*)d_in[7];
  const float* Vw1      = (const float*)d_in[8];
  const float* Vb1      = (const float*)d_in[9];
  const float* Vw2      = (const float*)d_in[10];
  const float* Vb2      = (const float*)d_in[11];
  float* out = (float*)d_out;

  char* ws = (char*)d_ws;
  float*  sW     = (float*)(ws);                     // 1 MB
  float*  vpart  = (float*)(ws + 1048576);           // 2 x 4 KB
  __bf16* W1b_bf = (__bf16*)(ws + 1057792);          // 64 KB
  __bf16* W2_bf  = (__bf16*)(ws + 1123328);          // 128 KB

  prep_pack_kernel<<<112, 256, 0, stream>>>(states, W1, b1, W2, Vw1, Vb1,
                                            Vw2, sW, vpart, W1b_bf, W2_bf);
  main_kernel<<<B_TOT, 512, 0, stream>>>(agent_qs, b2, W3, b3, Vb2, sW,
                                         vpart, W1b_bf, W2_bf, out);
}

// Round 10
// 140.088 us; speedup vs baseline: 1.0507x; 1.0507x over previous
//
#include <hip/hip_runtime.h>

// SQDDPG mixer, MI355X. Round 10: M-partitioned waves in main — wave w owns
// rows 16w..16w+15 and ALL 256 cols. h1 becomes wave-private (3 barriers
// total), layer-2 ds_reads 128->16/wave (af hoisted), adv complete per wave,
// B-frag streams shared across waves (L1). Envelope = R5: 4-wave blocks,
// 2-pass M=64, ~37 KB LDS, 4 blocks/CU, (256,4), u-width 4 (regs ~100).
//
// Frozen validated facts (R2..R8 passes): threefry partitionable,
// bits=o0^o1, counter (0, b*128+n); stable ranks; coalition slot j <-
// qs[inv_l[j]]; output agent n reads prefix-row pos_l[n]; A-frag
// A[m=l15][k=t*32+q*8+j]; C-frag row=q*4+r col=l15; B-frag pack: slot
// (t,u,L) elem j -> B[k=t*32+(L>>4)*8+j][n=u*16+(L&15)]; h1 scatter
// formula with row-tile = w; gather idx = (s>>3)*64+(s&7)*8+pos.

#define A_N   8
#define NA_N  16
#define S_N   16
#define SD    256
#define EMB   256
#define B_TOT 1024

typedef __bf16 bf16x8 __attribute__((ext_vector_type(8)));
typedef float  f32x4  __attribute__((ext_vector_type(4)));

__device__ __forceinline__ f32x4 splat4(float v) {
  f32x4 x; x[0] = v; x[1] = v; x[2] = v; x[3] = v; return x;
}
__device__ __forceinline__ bf16x8 zero8() {
  bf16x8 z;
#pragma unroll
  for (int j = 0; j < 8; ++j) z[j] = (__bf16)0.0f;
  return z;
}

// ---------------------------------------------------------------------------
// JAX threefry2x32, key = (0, 42); partitionable draw: bits = o0 ^ o1.
// ---------------------------------------------------------------------------
__device__ __forceinline__ float jax_uniform(unsigned idx) {
  const unsigned ks0 = 0u, ks1 = 42u, ks2 = 0x1BD11BDAu ^ 42u;
  unsigned x0 = 0u + ks0;
  unsigned x1 = idx + ks1;
#define TF_RND(r) { x0 += x1; x1 = (x1 << (r)) | (x1 >> (32 - (r))); x1 ^= x0; }
  TF_RND(13) TF_RND(15) TF_RND(26) TF_RND(6)  x0 += ks1; x1 += ks2 + 1u;
  TF_RND(17) TF_RND(29) TF_RND(16) TF_RND(24) x0 += ks2; x1 += ks0 + 2u;
  TF_RND(13) TF_RND(15) TF_RND(26) TF_RND(6)  x0 += ks0; x1 += ks1 + 3u;
  TF_RND(17) TF_RND(29) TF_RND(16) TF_RND(24) x0 += ks1; x1 += ks2 + 4u;
  TF_RND(13) TF_RND(15) TF_RND(26) TF_RND(6)  x0 += ks2; x1 += ks0 + 5u;
#undef TF_RND
  const unsigned bits = x0 ^ x1;
  return __uint_as_float((bits >> 9) | 0x3F800000u) - 1.0f;
}

// ---------------------------------------------------------------------------
// One launch: blocks 0..47 pack W1b_bf + W2_bf; blocks 48..111 = MFMA prep
// (16 M-tiles x 4 N-strips of [W1top|Vw1], B-frags built on the fly).
// Strips 0,1 -> sW; strips 2,3 -> relu()*Vw2 reduced -> vpart[ni-2][row].
// (Unchanged from R8 — proven.)
// ---------------------------------------------------------------------------
__global__ __launch_bounds__(256) void prep_pack_kernel(
    const float* __restrict__ states, const float* __restrict__ W1,
    const float* __restrict__ b1, const float* __restrict__ W2,
    const float* __restrict__ Vw1, const float* __restrict__ Vb1,
    const float* __restrict__ Vw2, float* __restrict__ sW,
    float* __restrict__ vpart, __bf16* __restrict__ W1b_bf,
    __bf16* __restrict__ W2_bf) {
  const int n = threadIdx.x;

  if (blockIdx.x < 48) {
    const int ts = blockIdx.x * 256 + n;            // 0..12287
    if (ts < 4096) {                                // W1 bottom: t=0..3
      const int t = ts >> 10, rem = ts & 1023, u = rem >> 6, L = rem & 63;
      const int q = L >> 4, l15 = L & 15;
#pragma unroll
      for (int j = 0; j < 8; ++j) {
        const int k = t * 32 + q * 8 + j, nn = u * 16 + l15;
        W1b_bf[ts * 8 + j] = (__bf16)W1[(SD + k) * EMB + nn];
      }
    } else {                                        // W2: t=0..7
      const int ts2 = ts - 4096;
      const int t = ts2 >> 10, rem = ts2 & 1023, u = rem >> 6, L = rem & 63;
      const int q = L >> 4, l15 = L & 15;
#pragma unroll
      for (int j = 0; j < 8; ++j) {
        const int k = t * 32 + q * 8 + j, nn = u * 16 + l15;
        W2_bf[ts2 * 8 + j] = (__bf16)W2[k * EMB + nn];
      }
    }
    return;
  }

  __shared__ float vred[4][64];
  const int blk = blockIdx.x - 48;  // 0..63
  const int mi = blk >> 2;          // 0..15
  const int ni = blk & 3;           // 0..3
  const int w = n >> 6, L = n & 63, q = L >> 4, l15 = L & 15;

  f32x4 acc[4][2];
#pragma unroll
  for (int ui = 0; ui < 2; ++ui) {
    const int col = (ni * 8 + w * 2 + ui) * 16 + l15;  // 0..511
    const float bias = (col < EMB) ? b1[col] : Vb1[col - EMB];
#pragma unroll
    for (int mt = 0; mt < 4; ++mt) acc[mt][ui] = splat4(bias);
  }

#pragma unroll 2
  for (int t = 0; t < 8; ++t) {
    bf16x8 bfr[2];
#pragma unroll
    for (int ui = 0; ui < 2; ++ui) {
      const int nn = (ni * 8 + w * 2 + ui) * 16 + l15;  // 0..511
#pragma unroll
      for (int j = 0; j < 8; ++j) {
        const int k = t * 32 + q * 8 + j;
        const float v = (nn < EMB) ? W1[k * EMB + nn]
                                   : Vw1[k * EMB + (nn - EMB)];
        bfr[ui][j] = (__bf16)v;
      }
    }
#pragma unroll
    for (int mt = 0; mt < 4; ++mt) {
      const float* srow =
          &states[(mi * 64 + mt * 16 + l15) * SD + t * 32 + q * 8];
      bf16x8 af;
#pragma unroll
      for (int j = 0; j < 8; ++j) af[j] = (__bf16)srow[j];
#pragma unroll
      for (int ui = 0; ui < 2; ++ui)
        acc[mt][ui] = __builtin_amdgcn_mfma_f32_16x16x32_bf16(
            af, bfr[ui], acc[mt][ui], 0, 0, 0);
    }
  }

  if (ni < 2) {
#pragma unroll
    for (int ui = 0; ui < 2; ++ui) {
      const int col = (ni * 8 + w * 2 + ui) * 16 + l15;
#pragma unroll
      for (int mt = 0; mt < 4; ++mt)
#pragma unroll
        for (int r = 0; r < 4; ++r)
          sW[(mi * 64 + mt * 16 + q * 4 + r) * EMB + col] = acc[mt][ui][r];
    }
  } else {
#pragma unroll
    for (int mt = 0; mt < 4; ++mt) {
#pragma unroll
      for (int r = 0; r < 4; ++r) {
        float p = 0.f;
#pragma unroll
        for (int ui = 0; ui < 2; ++ui) {
          const int colV = (ni * 8 + w * 2 + ui) * 16 + l15 - EMB;
          p = fmaf(fmaxf(acc[mt][ui][r], 0.f), Vw2[colV], p);
        }
#pragma unroll
        for (int off = 1; off < 16; off <<= 1) p += __shfl_xor(p, off);
        if (l15 == 0) vred[w][mt * 16 + q * 4 + r] = p;
      }
    }
    __syncthreads();
    if (n < 64)
      vpart[(ni - 2) * B_TOT + mi * 64 + n] =
          vred[0][n] + vred[1][n] + vred[2][n] + vred[3][n];
  }
}

// ---------------------------------------------------------------------------
// Main: 1024 blocks (one per b), 256 threads = 4 waves. Two passes of M=64.
// Wave w owns rows 16w..16w+15 (tile mt=w), all 256 cols in 4 u-chunks.
// h1 is wave-private -> only 3 __syncthreads total.
// ---------------------------------------------------------------------------
__global__ __launch_bounds__(256, 4) void main_kernel(
    const float* __restrict__ agent_qs, const float* __restrict__ b2g,
    const float* __restrict__ W3, const float* __restrict__ b3,
    const float* __restrict__ Vb2, const float* __restrict__ sW,
    const float* __restrict__ vpart, const __bf16* __restrict__ W1b_bf,
    const __bf16* __restrict__ W2_bf, float* __restrict__ out) {
  __shared__ bf16x8 h1_l[32 * 64];      // 32 KB: layer2 A-frags (M=64,K=256)
  __shared__ __attribute__((aligned(16))) __bf16 qs_bf[A_N * NA_N];
  __shared__ float u_l[128];
  __shared__ int   inv_l[128];          // inv_l[s*8+a] = rank of agent a
  __shared__ int   pos_l[128];          // pos_l[s*8+r] = agent with rank r
  __shared__ float sW_l[EMB], b2_l[EMB], w3_l[EMB];
  __shared__ float adv_l[128];          // [p*64 + w*16 + q*4 + r]

  const int b = blockIdx.x;
  const int n = threadIdx.x;
  const int w = n >> 6, L = n & 63, q = L >> 4, l15 = L & 15;

  if (n < 128) {
    qs_bf[n] = (__bf16)agent_qs[b * 128 + n];
    u_l[n] = jax_uniform((unsigned)(b * 128 + n));
  }
  sW_l[n] = sW[b * EMB + n];
  b2_l[n] = b2g[n];
  w3_l[n] = W3[n];
  __syncthreads();

  if (n < 128) {
    const int s = n >> 3, a = n & 7;
    const float u = u_l[n];
    int r = 0;
#pragma unroll
    for (int a2 = 0; a2 < A_N; ++a2) {
      const float u2 = u_l[s * 8 + a2];
      r += (u2 < u || (u2 == u && a2 < a)) ? 1 : 0;
    }
    inv_l[n] = r;
    pos_l[s * 8 + r] = a;
  }
  __syncthreads();

  const int i_pref  = l15 & 7;     // prefix length of this lane's A-row
  const int sl_half = l15 >> 3;    // which s within the row-tile pair
  const int jq      = q >> 1;      // jcoal low bit
  const int na0     = (q & 1) * 8; // action sub-block

  __bf16* h1e = (__bf16*)h1_l;

#pragma unroll 1
  for (int p = 0; p < 2; ++p) {
    // ---- layer 1 A-frags for rows tile w (hoisted, 4 LDS reads) ----
    bf16x8 afl[4];
#pragma unroll
    for (int t = 0; t < 4; ++t) {
      const int jcoal = t * 2 + jq;
      const int ag = inv_l[(p * 8 + w * 2 + sl_half) * 8 + jcoal];
      const bf16x8 qv = *(const bf16x8*)&qs_bf[ag * NA_N + na0];
      afl[t] = (jcoal <= i_pref) ? qv : zero8();
    }

    // ---- layer 1: rows 16, all 256 cols in 4 u-chunks ----
#pragma unroll 1
    for (int uc = 0; uc < 4; ++uc) {
      f32x4 acc[4];
#pragma unroll
      for (int ui = 0; ui < 4; ++ui)
        acc[ui] = splat4(sW_l[(uc * 4 + ui) * 16 + l15]);
#pragma unroll
      for (int t = 0; t < 4; ++t) {
#pragma unroll
        for (int ui = 0; ui < 4; ++ui) {
          const bf16x8 bfr = *(const bf16x8*)
              &W1b_bf[((t * 16 + uc * 4 + ui) * 64 + L) * 8];
          acc[ui] = __builtin_amdgcn_mfma_f32_16x16x32_bf16(
              afl[t], bfr, acc[ui], 0, 0, 0);
        }
      }
      // relu -> bf16 scatter into own row-tile of h1 (frozen formula, mt=w)
#pragma unroll
      for (int ui = 0; ui < 4; ++ui) {
        const int c = (uc * 4 + ui) * 16 + l15;
        const int t2 = c >> 5, q2 = (c >> 3) & 3, j2 = l15 & 7;
#pragma unroll
        for (int r = 0; r < 4; ++r) {
          const float v = fmaxf(acc[ui][r], 0.f);
          h1e[(((t2 * 4 + w) * 64) + q2 * 16 + q * 4 + r) * 8 + j2] =
              (__bf16)v;
        }
      }
    }

    // h1 row-tile w is wave-private: order own LDS writes before reads.
    asm volatile("s_waitcnt lgkmcnt(0)\n" ::: "memory");

    // ---- layer 2 A-frags for rows tile w (hoisted, 8 LDS reads) ----
    bf16x8 af2[8];
#pragma unroll
    for (int t = 0; t < 8; ++t) af2[t] = h1_l[(t * 4 + w) * 64 + L];

    float psum[4] = {0.f, 0.f, 0.f, 0.f};
#pragma unroll 1
    for (int uc = 0; uc < 4; ++uc) {
      f32x4 acc[4];
#pragma unroll
      for (int ui = 0; ui < 4; ++ui)
        acc[ui] = splat4(b2_l[(uc * 4 + ui) * 16 + l15]);
#pragma unroll
      for (int t = 0; t < 8; ++t) {
#pragma unroll
        for (int ui = 0; ui < 4; ++ui) {
          const bf16x8 bfr = *(const bf16x8*)
              &W2_bf[((t * 16 + uc * 4 + ui) * 64 + L) * 8];
          acc[ui] = __builtin_amdgcn_mfma_f32_16x16x32_bf16(
              af2[t], bfr, acc[ui], 0, 0, 0);
        }
      }
#pragma unroll
      for (int ui = 0; ui < 4; ++ui) {
        const float w3v = w3_l[(uc * 4 + ui) * 16 + l15];
#pragma unroll
        for (int r = 0; r < 4; ++r)
          psum[r] = fmaf(fmaxf(acc[ui][r], 0.f), w3v, psum[r]);
      }
    }

    // ---- complete adv for own rows: reduce 16 lanes, store direct ----
#pragma unroll
    for (int r = 0; r < 4; ++r) {
      float sum = psum[r];
#pragma unroll
      for (int off = 1; off < 16; off <<= 1) sum += __shfl_xor(sum, off);
      if (l15 == 0) adv_l[p * 64 + w * 16 + q * 4 + r] = sum;
    }
    // no barrier: next pass touches only this wave's h1 rows / adv rows
  }
  __syncthreads();  // adv_l complete across waves

  // ---- gather: agent a reads row (s>>3)*64+(s&7)*8+pos_l[s*8+a] ----
  if (n < A_N) {
    float sh = 0.f;
#pragma unroll
    for (int s = 0; s < S_N; ++s)
      sh += adv_l[(s >> 3) * 64 + (s & 7) * 8 + pos_l[s * 8 + n]];
    out[b * A_N + n] = sh * (1.f / 16.f) + b3[0] + Vb2[0] +
                       vpart[b] + vpart[B_TOT + b];
  }
}

// ---------------------------------------------------------------------------
extern "C" void kernel_launch(void* const* d_in, const int* in_sizes, int n_in,
                              void* d_out, int out_size, void* d_ws,
                              size_t ws_size, hipStream_t stream) {
  const float* states   = (const float*)d_in[0];
  const float* agent_qs = (const float*)d_in[1];
  const float* W1       = (const float*)d_in[2];
  const float* b1       = (const float*)d_in[3];
  const float* W2       = (const float*)d_in[4];
  const float* b2       = (const float*)d_in[5];
  const float* W3       = (const float*)d_in[6];
  const float* b3       = (const float*)d_in[7];
  const float* Vw1      = (const float*)d_in[8];
  const float* Vb1      = (const float*)d_in[9];
  const float* Vw2      = (const float*)d_in[10];
  const float* Vb2      = (const float*)d_in[11];
  float* out = (float*)d_out;

  char* ws = (char*)d_ws;
  float*  sW     = (float*)(ws);                     // 1 MB
  float*  vpart  = (float*)(ws + 1048576);           // 2 x 4 KB
  __bf16* W1b_bf = (__bf16*)(ws + 1057792);          // 64 KB
  __bf16* W2_bf  = (__bf16*)(ws + 1123328);          // 128 KB

  prep_pack_kernel<<<112, 256, 0, stream>>>(states, W1, b1, W2, Vw1, Vb1,
                                            Vw2, sW, vpart, W1b_bf, W2_bf);
  main_kernel<<<B_TOT, 256, 0, stream>>>(agent_qs, b2, W3, b3, Vb2, sW,
                                         vpart, W1b_bf, W2_bf, out);
}